// Round 1
// baseline (214.758 us; speedup 1.0000x reference)
//
#include <hip/hip_runtime.h>
#include <hip/hip_bf16.h>
#include <stdint.h>

// Problem constants
#define Bsz 2
#define Hn  16
#define Ln  1024
#define Dn  64
#define Rn  16
#define En  4

typedef short short8 __attribute__((ext_vector_type(8)));
typedef float f32x4  __attribute__((ext_vector_type(4)));

__device__ __forceinline__ unsigned short f32_to_bf16_rne(float f) {
    union { float f; uint32_t u; } x; x.f = f;
    uint32_t u = x.u;
    u += 0x7FFFu + ((u >> 16) & 1u);   // round-to-nearest-even
    return (unsigned short)(u >> 16);
}

// ---------------------------------------------------------------------------
// Kernel 1: u[b,h,l,r,e] = sum_d Q[b,h,l,d]*A1[r,h,d,e]   (z==0)
//           v[b,h,m,r,e] = sum_d K[b,h,m,d]*A2[r,h,e,d]   (z==1)
// Layout in ws: [bh][l][r*4+e] contiguous (re fastest) -> coalesced rows of 64.
// Grid: (L/16, B*H, 2), block 256.
// ---------------------------------------------------------------------------
__global__ __launch_bounds__(256) void uv_kernel(
    const float* __restrict__ Q, const float* __restrict__ K,
    const float* __restrict__ A1, const float* __restrict__ A2,
    float* __restrict__ ws_u, float* __restrict__ ws_v)
{
    __shared__ float Xs[16 * 68];          // 16 rows x 64 f32, pad->68 (bank shift 4)
    __shared__ float Ah[16 * 65 * 4];      // [r][d] as float4, stride 65 f4 per r

    const int tid = threadIdx.x;
    const int bh  = blockIdx.y;
    const int h   = bh & 15;
    const int l0  = blockIdx.x * 16;
    const int isV = blockIdx.z;

    const float* X = (isV ? K : Q) + (size_t)bh * Ln * Dn;

    // stage 16 X rows (256 float4 total, 1 per thread)
    {
        const int row = tid >> 4, c4 = tid & 15;
        const float4 v = *(const float4*)&X[(size_t)(l0 + row) * Dn + c4 * 4];
        *(float4*)&Xs[row * 68 + c4 * 4] = v;
    }
    // stage A-slice for this head as Ah[r][d][e] (float4 over e)
    if (!isV) {
        #pragma unroll
        for (int i = 0; i < 4; ++i) {
            const int p = tid + i * 256;           // 0..1023
            const int r = p >> 6, d = p & 63;
            const float4 v = *(const float4*)&A1[(((size_t)r * Hn + h) * Dn + d) * En];
            *(float4*)&Ah[(r * 65 + d) * 4] = v;
        }
    } else {
        #pragma unroll
        for (int i = 0; i < 4; ++i) {
            const int p = tid + i * 256;
            const int r = p >> 6, d = p & 63;
            float4 v;
            v.x = A2[(((size_t)r * Hn + h) * En + 0) * Dn + d];
            v.y = A2[(((size_t)r * Hn + h) * En + 1) * Dn + d];
            v.z = A2[(((size_t)r * Hn + h) * En + 2) * Dn + d];
            v.w = A2[(((size_t)r * Hn + h) * En + 3) * Dn + d];
            *(float4*)&Ah[(r * 65 + d) * 4] = v;
        }
    }
    __syncthreads();

    // thread t: li = t>>4 (row), r = t&15; computes 4 outputs (e=0..3)
    const int li = tid >> 4, r = tid & 15;
    float ax = 0.f, ay = 0.f, az = 0.f, aw = 0.f;
    #pragma unroll
    for (int d = 0; d < Dn; ++d) {
        const float x = Xs[li * 68 + d];
        const float4 a = *(const float4*)&Ah[(r * 65 + d) * 4];
        ax += x * a.x; ay += x * a.y; az += x * a.z; aw += x * a.w;
    }
    float* dst = (isV ? ws_v : ws_u);
    float4 o; o.x = ax; o.y = ay; o.z = az; o.w = aw;
    *(float4*)&dst[((size_t)bh * Ln + l0 + li) * 64 + r * 4] = o;
}

// ---------------------------------------------------------------------------
// Kernel 2: out[bh,l,m] = (QK^T + u[l,rid]·v[m,rid]) * valid(rid)
// One block per 64x64 output tile. 4 waves; wave w owns l-rows w*16..w*16+15,
// sweeps 4 m-subtiles. Base GEMM via mfma_f32_16x16x32_bf16 (2 k-steps).
// Grid: (L/64, L/64, B*H), block 256.
// ---------------------------------------------------------------------------
__global__ __launch_bounds__(256) void score_kernel(
    const float* __restrict__ Q, const float* __restrict__ K,
    const int* __restrict__ rid,
    const float* __restrict__ ws_u, const float* __restrict__ ws_v,
    float* __restrict__ out)
{
    __shared__ unsigned short Qs[64 * 72];   // bf16, row stride 72 (pad 8)
    __shared__ unsigned short Ks[64 * 72];
    __shared__ float us[64 * 68];            // f32, row stride 68 (pad 4)
    __shared__ float vs[64 * 68];

    const int tid = threadIdx.x;
    const int bh  = blockIdx.z;
    const int b   = bh >> 4;
    const int m0  = blockIdx.x * 64;
    const int l0  = blockIdx.y * 64;

    const size_t qkBase = (size_t)bh * Ln * Dn;
    const size_t uvBase = (size_t)bh * Ln * 64;

    // stage: Q,K tiles (f32->bf16) and u,v tiles (f32). 1024 float4 each.
    #pragma unroll
    for (int i = 0; i < 4; ++i) {
        const int p = tid + i * 256;        // 0..1023
        const int row = p >> 4, c4 = p & 15;
        const float4 q = *(const float4*)&Q[qkBase + (size_t)(l0 + row) * Dn + c4 * 4];
        const float4 k = *(const float4*)&K[qkBase + (size_t)(m0 + row) * Dn + c4 * 4];
        ushort4 qb, kb;
        qb.x = f32_to_bf16_rne(q.x); qb.y = f32_to_bf16_rne(q.y);
        qb.z = f32_to_bf16_rne(q.z); qb.w = f32_to_bf16_rne(q.w);
        kb.x = f32_to_bf16_rne(k.x); kb.y = f32_to_bf16_rne(k.y);
        kb.z = f32_to_bf16_rne(k.z); kb.w = f32_to_bf16_rne(k.w);
        *(ushort4*)&Qs[row * 72 + c4 * 4] = qb;
        *(ushort4*)&Ks[row * 72 + c4 * 4] = kb;
        const float4 u = *(const float4*)&ws_u[uvBase + (size_t)(l0 + row) * 64 + c4 * 4];
        const float4 v = *(const float4*)&ws_v[uvBase + (size_t)(m0 + row) * 64 + c4 * 4];
        *(float4*)&us[row * 68 + c4 * 4] = u;
        *(float4*)&vs[row * 68 + c4 * 4] = v;
    }
    __syncthreads();

    const int w    = tid >> 6;
    const int lane = tid & 63;
    const int quad = lane >> 4;
    const int ln   = lane & 15;

    f32x4 acc[4];
    #pragma unroll
    for (int t = 0; t < 4; ++t) { f32x4 z = {0.f, 0.f, 0.f, 0.f}; acc[t] = z; }

    // A-frag: Q row (w*16+ln), k = s*32 + quad*8 + j ; B-frag: K row (t*16+ln)
    #pragma unroll
    for (int s = 0; s < 2; ++s) {
        const short8 aF = *(const short8*)&Qs[(w * 16 + ln) * 72 + s * 32 + quad * 8];
        #pragma unroll
        for (int t = 0; t < 4; ++t) {
            const short8 bF = *(const short8*)&Ks[(t * 16 + ln) * 72 + s * 32 + quad * 8];
            acc[t] = __builtin_amdgcn_mfma_f32_16x16x32_bf16(aF, bF, acc[t], 0, 0, 0);
        }
    }

    // epilogue: D layout row(l) = quad*4+reg (A side), col(m) = ln (B side)
    #pragma unroll
    for (int t = 0; t < 4; ++t) {
        const int m_local = t * 16 + ln;
        const int m = m0 + m_local;
        #pragma unroll
        for (int reg = 0; reg < 4; ++reg) {
            const int l_local = w * 16 + quad * 4 + reg;
            const int l = l0 + l_local;
            const int rv = rid[((size_t)b * Ln + l) * Ln + m];
            const bool valid = (rv >= 0) && (rv < Rn);
            const int r = valid ? rv : 0;
            const float4 uu = *(const float4*)&us[l_local * 68 + r * 4];
            const float4 vv = *(const float4*)&vs[m_local * 68 + r * 4];
            const float low = uu.x * vv.x + uu.y * vv.y + uu.z * vv.z + uu.w * vv.w;
            const float res = valid ? (acc[t][reg] + low) : 0.f;
            out[((size_t)bh * Ln + l) * Ln + m] = res;
        }
    }
}

extern "C" void kernel_launch(void* const* d_in, const int* in_sizes, int n_in,
                              void* d_out, int out_size, void* d_ws, size_t ws_size,
                              hipStream_t stream) {
    const float* Q   = (const float*)d_in[0];
    const float* K   = (const float*)d_in[1];
    const int*   rid = (const int*)d_in[2];
    const float* A1  = (const float*)d_in[3];
    const float* A2  = (const float*)d_in[4];
    float* out = (float*)d_out;

    float* ws_u = (float*)d_ws;                              // B*H*L*64 f32 = 8 MB
    float* ws_v = ws_u + (size_t)Bsz * Hn * Ln * 64;         // another 8 MB

    uv_kernel<<<dim3(Ln / 16, Bsz * Hn, 2), 256, 0, stream>>>(Q, K, A1, A2, ws_u, ws_v);
    score_kernel<<<dim3(Ln / 64, Ln / 64, Bsz * Hn), 256, 0, stream>>>(Q, K, rid, ws_u, ws_v, out);
}

// Round 2
// 200.731 us; speedup vs baseline: 1.0699x; 1.0699x over previous
//
#include <hip/hip_runtime.h>
#include <hip/hip_bf16.h>
#include <stdint.h>

// Problem constants
#define Bsz 2
#define Hn  16
#define Ln  1024
#define Dn  64
#define Rn  16
#define En  4

typedef short short8 __attribute__((ext_vector_type(8)));
typedef float f32x4  __attribute__((ext_vector_type(4)));

__device__ __forceinline__ unsigned short f32_to_bf16_rne(float f) {
    union { float f; uint32_t u; } x; x.f = f;
    uint32_t u = x.u;
    u += 0x7FFFu + ((u >> 16) & 1u);   // round-to-nearest-even
    return (unsigned short)(u >> 16);
}

__device__ __forceinline__ float bf16_to_f32(unsigned short s) {
    union { uint32_t u; float f; } x; x.u = ((uint32_t)s) << 16;
    return x.f;
}

// ---------------------------------------------------------------------------
// Kernel 1: u[b,h,l,r,e] = sum_d Q[b,h,l,d]*A1[r,h,d,e]   (z==0)
//           v[b,h,m,r,e] = sum_d K[b,h,m,d]*A2[r,h,e,d]   (z==1)
// ws layout: [bh][l][r*4+e] contiguous, stored as bf16 (u,v ~0.16 scale;
// bf16 rel err 0.4% -> ~0.002 absolute in the low term, negligible).
// Grid: (L/16, B*H, 2), block 256.
// ---------------------------------------------------------------------------
__global__ __launch_bounds__(256) void uv_kernel(
    const float* __restrict__ Q, const float* __restrict__ K,
    const float* __restrict__ A1, const float* __restrict__ A2,
    unsigned short* __restrict__ ws_u, unsigned short* __restrict__ ws_v)
{
    __shared__ float Xs[16 * 68];          // 16 rows x 64 f32, pad->68
    __shared__ float Ah[16 * 65 * 4];      // [r][d] as float4, stride 65 f4 per r

    const int tid = threadIdx.x;
    const int bh  = blockIdx.y;
    const int h   = bh & 15;
    const int l0  = blockIdx.x * 16;
    const int isV = blockIdx.z;

    const float* X = (isV ? K : Q) + (size_t)bh * Ln * Dn;

    // stage 16 X rows (256 float4 total, 1 per thread)
    {
        const int row = tid >> 4, c4 = tid & 15;
        const float4 v = *(const float4*)&X[(size_t)(l0 + row) * Dn + c4 * 4];
        *(float4*)&Xs[row * 68 + c4 * 4] = v;
    }
    // stage A-slice for this head as Ah[r][d][e] (float4 over e)
    if (!isV) {
        #pragma unroll
        for (int i = 0; i < 4; ++i) {
            const int p = tid + i * 256;           // 0..1023
            const int r = p >> 6, d = p & 63;
            const float4 v = *(const float4*)&A1[(((size_t)r * Hn + h) * Dn + d) * En];
            *(float4*)&Ah[(r * 65 + d) * 4] = v;
        }
    } else {
        #pragma unroll
        for (int i = 0; i < 4; ++i) {
            const int p = tid + i * 256;
            const int r = p >> 6, d = p & 63;
            float4 v;
            v.x = A2[(((size_t)r * Hn + h) * En + 0) * Dn + d];
            v.y = A2[(((size_t)r * Hn + h) * En + 1) * Dn + d];
            v.z = A2[(((size_t)r * Hn + h) * En + 2) * Dn + d];
            v.w = A2[(((size_t)r * Hn + h) * En + 3) * Dn + d];
            *(float4*)&Ah[(r * 65 + d) * 4] = v;
        }
    }
    __syncthreads();

    // thread t: li = t>>4 (row), r = t&15; computes 4 outputs (e=0..3)
    const int li = tid >> 4, r = tid & 15;
    float ax = 0.f, ay = 0.f, az = 0.f, aw = 0.f;
    #pragma unroll
    for (int d = 0; d < Dn; ++d) {
        const float x = Xs[li * 68 + d];
        const float4 a = *(const float4*)&Ah[(r * 65 + d) * 4];
        ax += x * a.x; ay += x * a.y; az += x * a.z; aw += x * a.w;
    }
    unsigned short* dst = (isV ? ws_v : ws_u);
    ushort4 o;
    o.x = f32_to_bf16_rne(ax); o.y = f32_to_bf16_rne(ay);
    o.z = f32_to_bf16_rne(az); o.w = f32_to_bf16_rne(aw);
    *(ushort4*)&dst[((size_t)bh * Ln + l0 + li) * 64 + r * 4] = o;
}

// ---------------------------------------------------------------------------
// Kernel 2: out[bh,l,m] = (QK^T + u[l,rid]·v[m,rid]) * valid(rid)
// One block per 64x64 output tile, 4 waves. rid prefetched to registers
// before the MFMA loop (latency hides under staging+MFMA). u/v staged in
// LDS as bf16 (b64 gathers, <=2-way aliasing in-quad). Nontemporal stores.
// LDS = 2*9216 + 2*8704 = 35840 B -> 4 blocks/CU.
// Grid: (L/64, L/64, B*H), block 256.
// ---------------------------------------------------------------------------
__global__ __launch_bounds__(256, 4) void score_kernel(
    const float* __restrict__ Q, const float* __restrict__ K,
    const int* __restrict__ rid,
    const unsigned short* __restrict__ ws_u, const unsigned short* __restrict__ ws_v,
    float* __restrict__ out)
{
    __shared__ unsigned short Qs[64 * 72];   // bf16, row stride 72 (pad 8)
    __shared__ unsigned short Ks[64 * 72];
    __shared__ unsigned short us[64 * 68];   // bf16, row stride 68 (pad 4)
    __shared__ unsigned short vs[64 * 68];

    const int tid = threadIdx.x;
    const int bh  = blockIdx.z;
    const int b   = bh >> 4;
    const int m0  = blockIdx.x * 64;
    const int l0  = blockIdx.y * 64;

    const int w    = tid >> 6;
    const int lane = tid & 63;
    const int quad = lane >> 4;
    const int ln   = lane & 15;

    const size_t qkBase = (size_t)bh * Ln * Dn;
    const size_t uvBase = (size_t)bh * Ln * 64;

    // ---- prefetch the 16 rid values this thread needs (independent of LDS)
    int ridv[16];
    {
        const size_t ridRow0 = ((size_t)b * Ln + l0 + w * 16 + quad * 4) * Ln + m0 + ln;
        #pragma unroll
        for (int t = 0; t < 4; ++t)
            #pragma unroll
            for (int reg = 0; reg < 4; ++reg)
                ridv[t * 4 + reg] = rid[ridRow0 + (size_t)reg * Ln + t * 16];
    }

    // ---- stage: Q,K tiles (f32->bf16) and u,v tiles (bf16). coalesced.
    #pragma unroll
    for (int i = 0; i < 4; ++i) {
        const int p = tid + i * 256;        // 0..1023
        const int row = p >> 4, c4 = p & 15;
        const float4 q = *(const float4*)&Q[qkBase + (size_t)(l0 + row) * Dn + c4 * 4];
        const float4 k = *(const float4*)&K[qkBase + (size_t)(m0 + row) * Dn + c4 * 4];
        ushort4 qb, kb;
        qb.x = f32_to_bf16_rne(q.x); qb.y = f32_to_bf16_rne(q.y);
        qb.z = f32_to_bf16_rne(q.z); qb.w = f32_to_bf16_rne(q.w);
        kb.x = f32_to_bf16_rne(k.x); kb.y = f32_to_bf16_rne(k.y);
        kb.z = f32_to_bf16_rne(k.z); kb.w = f32_to_bf16_rne(k.w);
        *(ushort4*)&Qs[row * 72 + c4 * 4] = qb;
        *(ushort4*)&Ks[row * 72 + c4 * 4] = kb;
        const ushort4 u = *(const ushort4*)&ws_u[uvBase + (size_t)(l0 + row) * 64 + c4 * 4];
        const ushort4 v = *(const ushort4*)&ws_v[uvBase + (size_t)(m0 + row) * 64 + c4 * 4];
        *(ushort4*)&us[row * 68 + c4 * 4] = u;
        *(ushort4*)&vs[row * 68 + c4 * 4] = v;
    }
    __syncthreads();

    f32x4 acc[4];
    #pragma unroll
    for (int t = 0; t < 4; ++t) { f32x4 z = {0.f, 0.f, 0.f, 0.f}; acc[t] = z; }

    // A-frag: Q row (w*16+ln), k = s*32 + quad*8 + j ; B-frag: K row (t*16+ln)
    #pragma unroll
    for (int s = 0; s < 2; ++s) {
        const short8 aF = *(const short8*)&Qs[(w * 16 + ln) * 72 + s * 32 + quad * 8];
        #pragma unroll
        for (int t = 0; t < 4; ++t) {
            const short8 bF = *(const short8*)&Ks[(t * 16 + ln) * 72 + s * 32 + quad * 8];
            acc[t] = __builtin_amdgcn_mfma_f32_16x16x32_bf16(aF, bF, acc[t], 0, 0, 0);
        }
    }

    // ---- epilogue: D layout row(l) = quad*4+reg (A side), col(m) = ln (B side)
    #pragma unroll
    for (int t = 0; t < 4; ++t) {
        const int m_local = t * 16 + ln;
        const int m = m0 + m_local;
        #pragma unroll
        for (int reg = 0; reg < 4; ++reg) {
            const int l_local = w * 16 + quad * 4 + reg;
            const int l = l0 + l_local;
            const int rv = ridv[t * 4 + reg];
            const bool valid = (rv >= 0) && (rv < Rn);
            const int r = valid ? rv : 0;
            const ushort4 uu = *(const ushort4*)&us[l_local * 68 + r * 4];
            const ushort4 vv = *(const ushort4*)&vs[m_local * 68 + r * 4];
            const float low = bf16_to_f32(uu.x) * bf16_to_f32(vv.x)
                            + bf16_to_f32(uu.y) * bf16_to_f32(vv.y)
                            + bf16_to_f32(uu.z) * bf16_to_f32(vv.z)
                            + bf16_to_f32(uu.w) * bf16_to_f32(vv.w);
            const float res = valid ? (acc[t][reg] + low) : 0.f;
            __builtin_nontemporal_store(res, &out[((size_t)bh * Ln + l) * Ln + m]);
        }
    }
}

extern "C" void kernel_launch(void* const* d_in, const int* in_sizes, int n_in,
                              void* d_out, int out_size, void* d_ws, size_t ws_size,
                              hipStream_t stream) {
    const float* Q   = (const float*)d_in[0];
    const float* K   = (const float*)d_in[1];
    const int*   rid = (const int*)d_in[2];
    const float* A1  = (const float*)d_in[3];
    const float* A2  = (const float*)d_in[4];
    float* out = (float*)d_out;

    unsigned short* ws_u = (unsigned short*)d_ws;                 // B*H*L*64 bf16 = 4 MB
    unsigned short* ws_v = ws_u + (size_t)Bsz * Hn * Ln * 64;     // another 4 MB

    uv_kernel<<<dim3(Ln / 16, Bsz * Hn, 2), 256, 0, stream>>>(Q, K, A1, A2, ws_u, ws_v);
    score_kernel<<<dim3(Ln / 64, Ln / 64, Bsz * Hn), 256, 0, stream>>>(Q, K, rid, ws_u, ws_v, out);
}

// Round 3
// 200.729 us; speedup vs baseline: 1.0699x; 1.0000x over previous
//
#include <hip/hip_runtime.h>
#include <hip/hip_bf16.h>
#include <stdint.h>

// Problem constants
#define Bsz 2
#define Hn  16
#define Ln  1024
#define Dn  64
#define Rn  16
#define En  4

typedef short short8 __attribute__((ext_vector_type(8)));
typedef float f32x4  __attribute__((ext_vector_type(4)));

__device__ __forceinline__ unsigned short f32_to_bf16_rne(float f) {
    union { float f; uint32_t u; } x; x.f = f;
    uint32_t u = x.u;
    u += 0x7FFFu + ((u >> 16) & 1u);   // round-to-nearest-even
    return (unsigned short)(u >> 16);
}

__device__ __forceinline__ float bf16_to_f32(unsigned short s) {
    union { uint32_t u; float f; } x; x.u = ((uint32_t)s) << 16;
    return x.f;
}

// ---------------------------------------------------------------------------
// Kernel 1: u[b,h,l,r,e] = sum_d Q[b,h,l,d]*A1[r,h,d,e]   (z==0)
//           v[b,h,m,r,e] = sum_d K[b,h,m,d]*A2[r,h,e,d]   (z==1)
// ws layout: [bh][l][r*4+e] contiguous, stored as bf16.
// Grid: (L/16, B*H, 2), block 256.
// ---------------------------------------------------------------------------
__global__ __launch_bounds__(256) void uv_kernel(
    const float* __restrict__ Q, const float* __restrict__ K,
    const float* __restrict__ A1, const float* __restrict__ A2,
    unsigned short* __restrict__ ws_u, unsigned short* __restrict__ ws_v)
{
    __shared__ float Xs[16 * 68];          // 16 rows x 64 f32, pad->68
    __shared__ float Ah[16 * 65 * 4];      // [r][d] as float4, stride 65 f4 per r

    const int tid = threadIdx.x;
    const int bh  = blockIdx.y;
    const int h   = bh & 15;
    const int l0  = blockIdx.x * 16;
    const int isV = blockIdx.z;

    const float* X = (isV ? K : Q) + (size_t)bh * Ln * Dn;

    // stage 16 X rows (256 float4 total, 1 per thread)
    {
        const int row = tid >> 4, c4 = tid & 15;
        const float4 v = *(const float4*)&X[(size_t)(l0 + row) * Dn + c4 * 4];
        *(float4*)&Xs[row * 68 + c4 * 4] = v;
    }
    // stage A-slice for this head as Ah[r][d][e] (float4 over e)
    if (!isV) {
        #pragma unroll
        for (int i = 0; i < 4; ++i) {
            const int p = tid + i * 256;           // 0..1023
            const int r = p >> 6, d = p & 63;
            const float4 v = *(const float4*)&A1[(((size_t)r * Hn + h) * Dn + d) * En];
            *(float4*)&Ah[(r * 65 + d) * 4] = v;
        }
    } else {
        #pragma unroll
        for (int i = 0; i < 4; ++i) {
            const int p = tid + i * 256;
            const int r = p >> 6, d = p & 63;
            float4 v;
            v.x = A2[(((size_t)r * Hn + h) * En + 0) * Dn + d];
            v.y = A2[(((size_t)r * Hn + h) * En + 1) * Dn + d];
            v.z = A2[(((size_t)r * Hn + h) * En + 2) * Dn + d];
            v.w = A2[(((size_t)r * Hn + h) * En + 3) * Dn + d];
            *(float4*)&Ah[(r * 65 + d) * 4] = v;
        }
    }
    __syncthreads();

    // thread t: li = t>>4 (row), r = t&15; computes 4 outputs (e=0..3)
    const int li = tid >> 4, r = tid & 15;
    float ax = 0.f, ay = 0.f, az = 0.f, aw = 0.f;
    #pragma unroll
    for (int d = 0; d < Dn; ++d) {
        const float x = Xs[li * 68 + d];
        const float4 a = *(const float4*)&Ah[(r * 65 + d) * 4];
        ax += x * a.x; ay += x * a.y; az += x * a.z; aw += x * a.w;
    }
    unsigned short* dst = (isV ? ws_v : ws_u);
    ushort4 o;
    o.x = f32_to_bf16_rne(ax); o.y = f32_to_bf16_rne(ay);
    o.z = f32_to_bf16_rne(az); o.w = f32_to_bf16_rne(aw);
    *(ushort4*)&dst[((size_t)bh * Ln + l0 + li) * 64 + r * 4] = o;
}

// ---------------------------------------------------------------------------
// Kernel 2: out[bh,l,m] = (QK^T + u[l,rid]·v[m,rid]) * valid(rid)
// One block per 64x64 output tile, 4 waves. Wave w owns l-rows w*16..+15.
// Q A-fragments are loaded DIRECTLY from global (each wave's Q rows are
// private to it — no LDS round-trip needed): 2x dwordx4 per lane per k-step,
// converted to bf16 in-register. Only K / u / v are staged in LDS.
// rid prefetched to registers before the MFMA loop. Nontemporal stores.
// LDS = 9216 + 2*8704 = 26624 B -> LDS allows 6 blocks/CU; launch_bounds
// (256,5) caps VGPR at 102 -> 5 blocks/CU (20 waves, 62.5% occupancy).
// Grid: (L/64, L/64, B*H), block 256.
// ---------------------------------------------------------------------------
__global__ __launch_bounds__(256, 5) void score_kernel(
    const float* __restrict__ Q, const float* __restrict__ K,
    const int* __restrict__ rid,
    const unsigned short* __restrict__ ws_u, const unsigned short* __restrict__ ws_v,
    float* __restrict__ out)
{
    __shared__ unsigned short Ks[64 * 72];   // bf16, row stride 72 (pad 8)
    __shared__ unsigned short us[64 * 68];   // bf16, row stride 68 (pad 4)
    __shared__ unsigned short vs[64 * 68];

    const int tid = threadIdx.x;
    const int bh  = blockIdx.z;
    const int b   = bh >> 4;
    const int m0  = blockIdx.x * 64;
    const int l0  = blockIdx.y * 64;

    const int w    = tid >> 6;
    const int lane = tid & 63;
    const int quad = lane >> 4;
    const int ln   = lane & 15;

    const size_t qkBase = (size_t)bh * Ln * Dn;
    const size_t uvBase = (size_t)bh * Ln * 64;

    // ---- direct A-operand loads: this lane's Q slice, 8 consecutive f32
    //      per k-step (A[m=ln][k=s*32+quad*8+j])
    float4 qa[2][2];
    #pragma unroll
    for (int s = 0; s < 2; ++s) {
        const float* qp = &Q[qkBase + (size_t)(l0 + w * 16 + ln) * Dn + s * 32 + quad * 8];
        qa[s][0] = *(const float4*)qp;
        qa[s][1] = *(const float4*)(qp + 4);
    }

    // ---- prefetch the 16 rid values this thread needs
    int ridv[16];
    {
        const size_t ridRow0 = ((size_t)b * Ln + l0 + w * 16 + quad * 4) * Ln + m0 + ln;
        #pragma unroll
        for (int t = 0; t < 4; ++t)
            #pragma unroll
            for (int reg = 0; reg < 4; ++reg)
                ridv[t * 4 + reg] = rid[ridRow0 + (size_t)reg * Ln + t * 16];
    }

    // ---- stage K (f32->bf16) and u,v (bf16) tiles into LDS. coalesced.
    #pragma unroll
    for (int i = 0; i < 4; ++i) {
        const int p = tid + i * 256;        // 0..1023
        const int row = p >> 4, c4 = p & 15;
        const float4 k = *(const float4*)&K[qkBase + (size_t)(m0 + row) * Dn + c4 * 4];
        ushort4 kb;
        kb.x = f32_to_bf16_rne(k.x); kb.y = f32_to_bf16_rne(k.y);
        kb.z = f32_to_bf16_rne(k.z); kb.w = f32_to_bf16_rne(k.w);
        *(ushort4*)&Ks[row * 72 + c4 * 4] = kb;
        const ushort4 u = *(const ushort4*)&ws_u[uvBase + (size_t)(l0 + row) * 64 + c4 * 4];
        const ushort4 v = *(const ushort4*)&ws_v[uvBase + (size_t)(m0 + row) * 64 + c4 * 4];
        *(ushort4*)&us[row * 68 + c4 * 4] = u;
        *(ushort4*)&vs[row * 68 + c4 * 4] = v;
    }

    // convert this lane's A-fragments while staging loads drain
    short8 aF[2];
    #pragma unroll
    for (int s = 0; s < 2; ++s) {
        #pragma unroll
        for (int j = 0; j < 4; ++j) {
            aF[s][j]     = (short)f32_to_bf16_rne(qa[s][0][j]);
            aF[s][4 + j] = (short)f32_to_bf16_rne(qa[s][1][j]);
        }
    }
    __syncthreads();

    f32x4 acc[4];
    #pragma unroll
    for (int t = 0; t < 4; ++t) { f32x4 z = {0.f, 0.f, 0.f, 0.f}; acc[t] = z; }

    // B-frag: K row (t*16+ln), k = s*32 + quad*8 + j
    #pragma unroll
    for (int s = 0; s < 2; ++s) {
        #pragma unroll
        for (int t = 0; t < 4; ++t) {
            const short8 bF = *(const short8*)&Ks[(t * 16 + ln) * 72 + s * 32 + quad * 8];
            acc[t] = __builtin_amdgcn_mfma_f32_16x16x32_bf16(aF[s], bF, acc[t], 0, 0, 0);
        }
    }

    // ---- epilogue: D layout row(l) = quad*4+reg (A side), col(m) = ln (B side)
    #pragma unroll
    for (int t = 0; t < 4; ++t) {
        const int m_local = t * 16 + ln;
        const int m = m0 + m_local;
        #pragma unroll
        for (int reg = 0; reg < 4; ++reg) {
            const int l_local = w * 16 + quad * 4 + reg;
            const int l = l0 + l_local;
            const int rv = ridv[t * 4 + reg];
            const bool valid = (rv >= 0) && (rv < Rn);
            const int r = valid ? rv : 0;
            const ushort4 uu = *(const ushort4*)&us[l_local * 68 + r * 4];
            const ushort4 vv = *(const ushort4*)&vs[m_local * 68 + r * 4];
            const float low = bf16_to_f32(uu.x) * bf16_to_f32(vv.x)
                            + bf16_to_f32(uu.y) * bf16_to_f32(vv.y)
                            + bf16_to_f32(uu.z) * bf16_to_f32(vv.z)
                            + bf16_to_f32(uu.w) * bf16_to_f32(vv.w);
            const float res = valid ? (acc[t][reg] + low) : 0.f;
            __builtin_nontemporal_store(res, &out[((size_t)bh * Ln + l) * Ln + m]);
        }
    }
}

extern "C" void kernel_launch(void* const* d_in, const int* in_sizes, int n_in,
                              void* d_out, int out_size, void* d_ws, size_t ws_size,
                              hipStream_t stream) {
    const float* Q   = (const float*)d_in[0];
    const float* K   = (const float*)d_in[1];
    const int*   rid = (const int*)d_in[2];
    const float* A1  = (const float*)d_in[3];
    const float* A2  = (const float*)d_in[4];
    float* out = (float*)d_out;

    unsigned short* ws_u = (unsigned short*)d_ws;                 // B*H*L*64 bf16 = 4 MB
    unsigned short* ws_v = ws_u + (size_t)Bsz * Hn * Ln * 64;     // another 4 MB

    uv_kernel<<<dim3(Ln / 16, Bsz * Hn, 2), 256, 0, stream>>>(Q, K, A1, A2, ws_u, ws_v);
    score_kernel<<<dim3(Ln / 64, Ln / 64, Bsz * Hn), 256, 0, stream>>>(Q, K, rid, ws_u, ws_v, out);
}